// Round 5
// baseline (333.061 us; speedup 1.0000x reference)
//
#include <hip/hip_runtime.h>
#include <hip/hip_bf16.h>

// ModulatedConv2d fused: B=8, CIN=COUT=64, K=3, H=W=256, SDIM=512
// Round 5: weights hoisted to registers (issued before staging, latency hidden).
//  Wave roles: wv = (wy = wv&1 -> y-row pair, cy = wv>>1 -> cout half).
//  Per wave: wfr[2ct][9kk][2half] = 36 bf16x8 (144 VGPR), acc[2y][2ct][4xt].
//  Inner loop: 8 ds_read_b128 + 16 reg-MFMA per (kk,half) — no global loads.
//  ws: wA bf16 [B][64cout][9][64cin] @0 (589824 B), s f32 [B][64] @589824

#define CIN   64
#define COUT  64
#define SDIM  512

typedef short bf16x8 __attribute__((ext_vector_type(8)));
typedef float f32x4  __attribute__((ext_vector_type(4)));
typedef unsigned short u16;
typedef unsigned short us8 __attribute__((ext_vector_type(8)));

static __device__ __forceinline__ u16 f2bf(float f) {
    union { float f; unsigned u; } v; v.f = f;
    unsigned r = v.u + 0x7FFF + ((v.u >> 16) & 1);   // RTN-even
    return (u16)(r >> 16);
}
static __device__ __forceinline__ float getc(const float4& f, int k) {
    return k == 0 ? f.x : k == 1 ? f.y : k == 2 ? f.z : f.w;
}

// ---------------- kernel 1: style modulation s[b][cin] ----------------
__global__ void k_style(const float* __restrict__ style, const float* __restrict__ mw,
                        const float* __restrict__ mb, float* __restrict__ s_out) {
    int b = blockIdx.x;            // 8 blocks x 256 threads
    int t = threadIdx.x;
    int cin = t & 63, seg = t >> 6;
    const float4* st = (const float4*)(style + (size_t)b * SDIM) + seg * 32;
    const float4* w  = (const float4*)(mw + (size_t)cin * SDIM) + seg * 32;
    float acc = 0.f;
#pragma unroll 8
    for (int i = 0; i < 32; i++) {
        float4 a = st[i], bb = w[i];
        acc += a.x * bb.x + a.y * bb.y + a.z * bb.z + a.w * bb.w;
    }
    __shared__ float red[4][64];
    red[seg][cin] = acc;
    __syncthreads();
    if (seg == 0) {
        float v = red[0][cin] + red[1][cin] + red[2][cin] + red[3][cin];
        s_out[b * CIN + cin] = v * 0.04419417382415922f + mb[cin];  // 1/sqrt(512)
    }
}

// ------------- kernel 2: modulate + demodulate -> bf16 wA[b][cout][kk][cin] -------------
__global__ void k_wdemod(const float* __restrict__ weight, const float* __restrict__ s,
                         u16* __restrict__ wA) {
    int bid = blockIdx.x;             // B*COUT = 512 blocks x 64 threads
    int b = bid >> 6, co = bid & 63;
    int cin = threadIdx.x;
    float sv = s[b * CIN + cin] * (1.0f / 24.0f);   // scale = 1/sqrt(64*9)
    const float* wp = weight + ((size_t)co * CIN + cin) * 9;
    float w[9]; float sq = 0.f;
#pragma unroll
    for (int k = 0; k < 9; k++) { w[k] = wp[k] * sv; sq += w[k] * w[k]; }
#pragma unroll
    for (int off = 32; off; off >>= 1) sq += __shfl_xor(sq, off, 64);
    float dm = 1.0f / sqrtf(sq + 1e-8f);
    u16* dst = wA + (((size_t)b * COUT + co) * 9) * 64 + cin;
#pragma unroll
    for (int k = 0; k < 9; k++) dst[k * 64] = f2bf(w[k] * dm);
}

// ------------- kernel 3: fused stage+conv+epilogue, weights-in-registers -------------
// block = 256 thr (4 waves); tile = one batch b, 4 y rows x 64 x, all 64 cout.
// LDS: bf16 X [yl=6][xl=72][cin=64], byte^=((xl&7)<<4) swizzle. 55296 B -> 2 blk/CU.
__global__ __launch_bounds__(256, 2) void k_conv2(
        const float* __restrict__ in, const u16* __restrict__ wA,
        float* __restrict__ out) {
    __shared__ __align__(16) u16 Xs[6 * 72 * 64];   // 55296 B

    int raw = blockIdx.x;
    int swz = (raw & 7) * 256 + (raw >> 3);         // XCD swizzle: batch per XCD
    int b = swz >> 8, r = swz & 255;
    int y0 = (r >> 2) * 4, x0 = (r & 3) * 64;
    int tid = threadIdx.x;
    int wv = tid >> 6, l = tid & 63, lr = l & 15, lg = l >> 4;
    int wy = wv & 1, cy = wv >> 1;

    // ---- issue all weight-fragment loads up front (latency hides under staging) ----
    const u16* wAb = wA + (size_t)b * (COUT * 9 * 64);
    bf16x8 wfr[2][9][2];
#pragma unroll
    for (int ct = 0; ct < 2; ct++)
#pragma unroll
        for (int kk = 0; kk < 9; kk++)
#pragma unroll
            for (int half = 0; half < 2; half++)
                wfr[ct][kk][half] = *(const bf16x8*)(
                    wAb + ((size_t)((cy * 2 + ct) * 16 + lr) * 9 + kk) * 64
                        + half * 32 + lg * 8);

    // ---- stage: 864 units = 6y x 18(x4) x 8(cin-group); unit loads 8x float4,
    //      register-transposes to 4x ds_write_b128 ([x][cin8] 16B each) ----
    const float* inb = in + (size_t)b * (CIN * 65536);
    for (int u = tid; u < 864; u += 256) {
        int cing = u & 7;
        int g = u >> 3;
        int x4 = g % 18, yy = g / 18;
        int y = y0 + yy - 1;
        int x = x0 - 4 + x4 * 4;                    // float4-aligned; fully in or out
        float4 f[8];
        if (y >= 0 && y < 256 && x >= 0 && x < 253) {
            const float* p = inb + (size_t)(cing * 8) * 65536 + (size_t)y * 256 + x;
#pragma unroll
            for (int j = 0; j < 8; j++) f[j] = *(const float4*)(p + (size_t)j * 65536);
        } else {
#pragma unroll
            for (int j = 0; j < 8; j++) f[j] = make_float4(0.f, 0.f, 0.f, 0.f);
        }
#pragma unroll
        for (int k = 0; k < 4; k++) {
            union { us8 v; unsigned w[4]; } pk;
#pragma unroll
            for (int p2 = 0; p2 < 4; p2++) {
                __hip_bfloat162 h = __float22bfloat162_rn(
                    make_float2(getc(f[2 * p2], k), getc(f[2 * p2 + 1], k)));
                unsigned wv_; __builtin_memcpy(&wv_, &h, 4);
                pk.w[p2] = wv_;
            }
            int xl = x4 * 4 + k;
            unsigned bo = (unsigned)(((yy * 72 + xl) * 64 + cing * 8) * 2)
                        ^ ((unsigned)(xl & 7) << 4);
            *(us8*)((char*)Xs + bo) = pk.v;
        }
    }
    __syncthreads();

    // ---- compute: pure LDS + register MFMA ----
    f32x4 acc[2][2][4];   // [yy][ct][xt]
#pragma unroll
    for (int yy = 0; yy < 2; yy++)
#pragma unroll
        for (int ct = 0; ct < 2; ct++)
#pragma unroll
            for (int xt = 0; xt < 4; xt++) acc[yy][ct][xt] = (f32x4){0.f, 0.f, 0.f, 0.f};

#pragma unroll
    for (int kk = 0; kk < 9; kk++) {
        const int dh = kk / 3, dw = kk % 3;
#pragma unroll
        for (int half = 0; half < 2; half++) {
            bf16x8 bfr[2][4];
#pragma unroll
            for (int yy = 0; yy < 2; yy++) {
                const int yl = wy * 2 + yy + dh;
#pragma unroll
                for (int xt = 0; xt < 4; xt++) {
                    int xl = xt * 16 + lr + dw + 3;
                    unsigned bo = (unsigned)(((yl * 72 + xl) * 64 + half * 32 + lg * 8) * 2)
                                ^ ((unsigned)(xl & 7) << 4);
                    bfr[yy][xt] = *(const bf16x8*)((const char*)Xs + bo);
                }
            }
#pragma unroll
            for (int ct = 0; ct < 2; ct++)
#pragma unroll
                for (int yy = 0; yy < 2; yy++)
#pragma unroll
                    for (int xt = 0; xt < 4; xt++)
                        acc[yy][ct][xt] = __builtin_amdgcn_mfma_f32_16x16x32_bf16(
                            wfr[ct][kk][half], bfr[yy][xt], acc[yy][ct][xt], 0, 0, 0);
        }
    }

    // ---- epilogue: per-wave LDS bounce -> float4 stores (full 64B lines) ----
    __syncthreads();                                 // all waves done reading Xs
    float* ep = ((float*)Xs) + wv * (16 * 68);       // 4352 B per wave, stride-68 rows
    int c = l >> 2, xq = l & 3;
    float* obase = out + (size_t)b * COUT * 65536;
#pragma unroll
    for (int ct = 0; ct < 2; ct++)
#pragma unroll
        for (int yy = 0; yy < 2; yy++) {
#pragma unroll
            for (int xt = 0; xt < 4; xt++)
#pragma unroll
                for (int q = 0; q < 4; q++)
                    ep[(lg * 4 + q) * 68 + xt * 16 + lr] = acc[yy][ct][xt][q];
            asm volatile("s_waitcnt lgkmcnt(0)" ::: "memory");
            float* ob = obase + (size_t)(cy * 32 + ct * 16 + c) * 65536
                      + (size_t)(y0 + wy * 2 + yy) * 256 + x0;
#pragma unroll
            for (int k = 0; k < 4; k++) {
                float4 v = *(const float4*)(ep + c * 68 + k * 16 + xq * 4);
                *(float4*)(ob + k * 16 + xq * 4) = v;
            }
        }
}

extern "C" void kernel_launch(void* const* d_in, const int* in_sizes, int n_in,
                              void* d_out, int out_size, void* d_ws, size_t ws_size,
                              hipStream_t stream) {
    const float* input      = (const float*)d_in[0];
    const float* style      = (const float*)d_in[1];
    const float* weight     = (const float*)d_in[2];
    const float* mod_weight = (const float*)d_in[3];
    const float* mod_bias   = (const float*)d_in[4];
    float* out = (float*)d_out;

    char* ws = (char*)d_ws;
    u16*   wA = (u16*)ws;                       // 589824 B
    float* s  = (float*)(ws + 589824);          // 2048 B

    k_style <<<8,    256, 0, stream>>>(style, mod_weight, mod_bias, s);
    k_wdemod<<<512,  64,  0, stream>>>(weight, s, wA);
    k_conv2 <<<2048, 256, 0, stream>>>(input, wA, out);
}